// Round 6
// baseline (207.641 us; speedup 1.0000x reference)
//
#include <hip/hip_runtime.h>
#include <hip/hip_bf16.h>

// WaveletBlock fused kernel (f32 in/out): DWT -> GEMM1(+bias,SiLU) -> GEMM2(+bias) -> IDWT
// R6: 32-pixel half-row tiles, 256-thread blocks (4 waves), grid 2048 (8 blocks/CU),
//   LDS exactly 16 KB (x_dwt -> feat -> y, XOR-swizzled) -> up to 10 blocks/CU capacity,
//   launch_bounds(256,6) -> ~24 waves/CU target. 16x16x32 MFMA, mt=4 / nt=2
//   (A-load:MFMA = 1:2). No manual prefetch (R5 showed the compiler defeats it).

typedef __bf16 bf16x8 __attribute__((ext_vector_type(8)));
typedef float  f32x4  __attribute__((ext_vector_type(4)));

__device__ __forceinline__ unsigned short f2bf(float f) {
  __hip_bfloat16 h = __float2bfloat16(f);
  return __builtin_bit_cast(unsigned short, h);
}
__device__ __forceinline__ float bf2f(unsigned short s) {
  union { unsigned int i; float f; } v; v.i = ((unsigned int)s) << 16; return v.f;
}
__device__ __forceinline__ float silu(float f) {
  return f / (1.0f + __expf(-f));
}
// Swizzled flat index into the 32x256 bf16 tile: 16B unit XOR'd with pix&31.
__device__ __forceinline__ int sw(int pix, int k) {
  return pix * 256 + ((((k >> 3) ^ pix) & 31) << 3) + (k & 7);
}
__device__ __forceinline__ bf16x8 ldw8(const float* __restrict__ p) {  // f32 fallback
  const float4 a = *(const float4*)p;
  const float4 b = *(const float4*)(p + 4);
  bf16x8 r;
  r[0] = (__bf16)a.x; r[1] = (__bf16)a.y; r[2] = (__bf16)a.z; r[3] = (__bf16)a.w;
  r[4] = (__bf16)b.x; r[5] = (__bf16)b.y; r[6] = (__bf16)b.z; r[7] = (__bf16)b.w;
  return r;
}

// Prelude: f32 -> bf16 weight conversion into workspace.
__global__ __launch_bounds__(256) void cvt_w(const float* __restrict__ w1,
                                             const float* __restrict__ w2,
                                             unsigned short* __restrict__ o) {
  const int i = (blockIdx.x * 256 + threadIdx.x) * 4;  // grid 64 x 256 covers 65536
  const float4 a = *(const float4*)(w1 + i);
  const float4 b = *(const float4*)(w2 + i);
  *(ushort4*)(o + i)         = make_ushort4(f2bf(a.x), f2bf(a.y), f2bf(a.z), f2bf(a.w));
  *(ushort4*)(o + 65536 + i) = make_ushort4(f2bf(b.x), f2bf(b.y), f2bf(b.z), f2bf(b.w));
}

template <bool WBF16>
__global__ __launch_bounds__(256, 6)
void wavelet_fused(const float* __restrict__ x,
                   const void* __restrict__ w1p,
                   const float* __restrict__ b1,
                   const void* __restrict__ w2p,
                   const float* __restrict__ b2,
                   float* __restrict__ out)
{
  // One buffer, three lives: x_dwt [pix][c4] -> feat [pix][o] -> y [pix][c4].
  __shared__ unsigned short lds[32 * 256];  // exactly 16 KiB (swizzled, no pad)

  const int t    = threadIdx.x;
  const int bid  = blockIdx.x;
  const int n    = bid >> 7;          // image (b*8+l); 128 blocks per image
  const int hh   = (bid >> 1) & 63;   // DWT row
  const int half = bid & 1;           // which 32-pixel half of the row

  const int ww  = t & 31;             // local pixel (phases 1/4)
  const int cg  = t >> 5;             // channel group 0..7 (8 input ch each)
  const int col = half * 32 + ww;     // global DWT column

  // ---------------- Phase 1: Haar DWT -> lds[ww][q*64+c] (swizzled) ----------------
  {
    const float* xb = x + ((size_t)n * 64 * 128 + (size_t)(2 * hh)) * 128 + 2 * col;
    float2 r0v[8], r1v[8];
    #pragma unroll
    for (int j = 0; j < 2; ++j)
      #pragma unroll
      for (int ci = 0; ci < 4; ++ci) {
        const float* p = xb + (size_t)(cg * 8 + j * 4 + ci) * (128 * 128);
        r0v[j * 4 + ci] = *(const float2*)p;          // (2hh,   2col / 2col+1)
        r1v[j * 4 + ci] = *(const float2*)(p + 128);  // (2hh+1, ...)
      }
    #pragma unroll
    for (int j = 0; j < 2; ++j) {
      const int c0 = cg * 8 + j * 4;
      float qv[4][4];
      #pragma unroll
      for (int ci = 0; ci < 4; ++ci) {
        const float x1 = r0v[j * 4 + ci].x, x3 = r0v[j * 4 + ci].y;
        const float x2 = r1v[j * 4 + ci].x, x4 = r1v[j * 4 + ci].y;
        qv[0][ci] = 0.5f * ((x1 + x2) + (x3 + x4));
        qv[1][ci] = 0.5f * ((x3 + x4) - (x1 + x2));
        qv[2][ci] = 0.5f * ((x2 + x4) - (x1 + x3));
        qv[3][ci] = 0.5f * ((x1 + x4) - (x2 + x3));
      }
      #pragma unroll
      for (int q = 0; q < 4; ++q) {
        ushort4 v = make_ushort4(f2bf(qv[q][0]), f2bf(qv[q][1]), f2bf(qv[q][2]), f2bf(qv[q][3]));
        *(ushort4*)(&lds[sw(ww, q * 64 + c0)]) = v;
      }
    }
  }
  __syncthreads();

  const int wv   = t >> 6;          // wave id: 64-row o/c4 slice
  const int r    = t & 15;          // MFMA row/col-in-tile
  const int quad = (t & 63) >> 4;   // MFMA quad

  const unsigned short* w1b16 = (const unsigned short*)w1p + (wv * 64 + r) * 256 + quad * 8;
  const unsigned short* w2b16 = (const unsigned short*)w2p + (wv * 64 + r) * 256 + quad * 8;
  const float*          w1b32 = (const float*)w1p + (wv * 64 + r) * 256 + quad * 8;
  const float*          w2b32 = (const float*)w2p + (wv * 64 + r) * 256 + quad * 8;

  // ---------------- Phase 2: GEMM1  D[o][pix] = conv_w . x_dwt; silu -> lds[pix][o] ----------------
  {
    f32x4 acc[4][2];
    #pragma unroll
    for (int mt = 0; mt < 4; ++mt)
      #pragma unroll
      for (int nt = 0; nt < 2; ++nt)
        acc[mt][nt] = (f32x4){0.0f, 0.0f, 0.0f, 0.0f};

    #pragma unroll
    for (int k0 = 0; k0 < 256; k0 += 32) {
      bf16x8 a[4], b[2];
      #pragma unroll
      for (int mt = 0; mt < 4; ++mt)   // A: conv_w rows o (L2-resident)
        a[mt] = WBF16 ? *(const bf16x8*)(w1b16 + mt * (16 * 256) + k0)
                      : ldw8(w1b32 + mt * (16 * 256) + k0);
      #pragma unroll
      for (int nt = 0; nt < 2; ++nt)   // B: x_dwt[pix][k] (ds_read_b128, swizzled)
        b[nt] = *(const bf16x8*)(&lds[sw(nt * 16 + r, quad * 8 + k0)]);
      #pragma unroll
      for (int mt = 0; mt < 4; ++mt)
        #pragma unroll
        for (int nt = 0; nt < 2; ++nt)
          acc[mt][nt] = __builtin_amdgcn_mfma_f32_16x16x32_bf16(a[mt], b[nt], acc[mt][nt], 0, 0, 0);
    }
    __syncthreads();  // all GEMM1 reads of lds done

    // Epilogue: lane holds 4 consecutive o (rows) at col pix -> b64 LDS write
    #pragma unroll
    for (int mt = 0; mt < 4; ++mt) {
      const int ob = wv * 64 + mt * 16 + quad * 4;
      const float4 bb = *(const float4*)(b1 + ob);
      #pragma unroll
      for (int nt = 0; nt < 2; ++nt) {
        const int pix = nt * 16 + r;
        ushort4 v;
        v.x = f2bf(silu(acc[mt][nt][0] + bb.x));
        v.y = f2bf(silu(acc[mt][nt][1] + bb.y));
        v.z = f2bf(silu(acc[mt][nt][2] + bb.z));
        v.w = f2bf(silu(acc[mt][nt][3] + bb.w));
        *(ushort4*)(&lds[sw(pix, ob)]) = v;
      }
    }
  }
  __syncthreads();

  // ---------------- Phase 3: GEMM2  D[c4][pix] = conv_out_w . feat -> lds[pix][c4] ----------------
  {
    f32x4 acc[4][2];
    #pragma unroll
    for (int mt = 0; mt < 4; ++mt)
      #pragma unroll
      for (int nt = 0; nt < 2; ++nt)
        acc[mt][nt] = (f32x4){0.0f, 0.0f, 0.0f, 0.0f};

    #pragma unroll
    for (int k0 = 0; k0 < 256; k0 += 32) {
      bf16x8 a[4], b[2];
      #pragma unroll
      for (int mt = 0; mt < 4; ++mt)
        a[mt] = WBF16 ? *(const bf16x8*)(w2b16 + mt * (16 * 256) + k0)
                      : ldw8(w2b32 + mt * (16 * 256) + k0);
      #pragma unroll
      for (int nt = 0; nt < 2; ++nt)   // B: feat[pix][k] (swizzled)
        b[nt] = *(const bf16x8*)(&lds[sw(nt * 16 + r, quad * 8 + k0)]);
      #pragma unroll
      for (int mt = 0; mt < 4; ++mt)
        #pragma unroll
        for (int nt = 0; nt < 2; ++nt)
          acc[mt][nt] = __builtin_amdgcn_mfma_f32_16x16x32_bf16(a[mt], b[nt], acc[mt][nt], 0, 0, 0);
    }
    __syncthreads();  // all GEMM2 reads of lds done

    #pragma unroll
    for (int mt = 0; mt < 4; ++mt) {
      const int cb = wv * 64 + mt * 16 + quad * 4;
      const float4 bb = *(const float4*)(b2 + cb);
      #pragma unroll
      for (int nt = 0; nt < 2; ++nt) {
        const int pix = nt * 16 + r;
        ushort4 v;
        v.x = f2bf(acc[mt][nt][0] + bb.x);
        v.y = f2bf(acc[mt][nt][1] + bb.y);
        v.z = f2bf(acc[mt][nt][2] + bb.z);
        v.w = f2bf(acc[mt][nt][3] + bb.w);
        *(ushort4*)(&lds[sw(pix, cb)]) = v;
      }
    }
  }
  __syncthreads();

  // ---------------- Phase 4: IDWT + coalesced float2 stores ----------------
  {
    float* ob_ = out + ((size_t)n * 64 * 128 + (size_t)(2 * hh)) * 128 + 2 * col;
    #pragma unroll
    for (int j = 0; j < 2; ++j) {
      const int c0 = cg * 8 + j * 4;
      unsigned short yb[4][4];
      #pragma unroll
      for (int q = 0; q < 4; ++q) {
        const ushort4 v = *(const ushort4*)(&lds[sw(ww, q * 64 + c0)]);
        yb[q][0] = v.x; yb[q][1] = v.y; yb[q][2] = v.z; yb[q][3] = v.w;
      }
      #pragma unroll
      for (int ci = 0; ci < 4; ++ci) {
        const float y1 = 0.5f * bf2f(yb[0][ci]);
        const float y2 = 0.5f * bf2f(yb[1][ci]);
        const float y3 = 0.5f * bf2f(yb[2][ci]);
        const float y4 = 0.5f * bf2f(yb[3][ci]);
        const float s14 = y1 + y4, s23 = y2 + y3;
        const float d14 = y1 - y4, d23 = y2 - y3;
        const float oa  = s14 - s23;  // (2hh,   2col)
        const float oc  = d14 + d23;  // (2hh,   2col+1)
        const float obv = d14 - d23;  // (2hh+1, 2col)
        const float od  = s14 + s23;  // (2hh+1, 2col+1)
        float* prow = ob_ + (size_t)(c0 + ci) * (128 * 128);
        *(float2*)prow         = make_float2(oa, oc);
        *(float2*)(prow + 128) = make_float2(obv, od);
      }
    }
  }
}

extern "C" void kernel_launch(void* const* d_in, const int* in_sizes, int n_in,
                              void* d_out, int out_size, void* d_ws, size_t ws_size,
                              hipStream_t stream) {
  (void)in_sizes; (void)n_in; (void)out_size;
  const float* x  = (const float*)d_in[0];
  const float* w1 = (const float*)d_in[1];
  const float* b1 = (const float*)d_in[2];
  const float* w2 = (const float*)d_in[3];
  const float* b2 = (const float*)d_in[4];
  float* o = (float*)d_out;

  if (ws_size >= 2u * 65536u * sizeof(unsigned short)) {
    unsigned short* wb = (unsigned short*)d_ws;
    cvt_w<<<dim3(64), dim3(256), 0, stream>>>(w1, w2, wb);
    wavelet_fused<true><<<dim3(16 * 64 * 2), dim3(256), 0, stream>>>(
        x, wb, b1, wb + 65536, b2, o);
  } else {
    wavelet_fused<false><<<dim3(16 * 64 * 2), dim3(256), 0, stream>>>(
        x, w1, b1, w2, b2, o);
  }
}

// Round 7
// 169.412 us; speedup vs baseline: 1.2257x; 1.2257x over previous
//
#include <hip/hip_runtime.h>
#include <hip/hip_bf16.h>

// WaveletBlock (f32 in/out): DWT -> GEMM1(+bias,SiLU) -> GEMM2(+bias) -> IDWT
// R7: SPLIT into two streaming kernels through a bf16 feat buffer in d_ws.
//   A: DWT -> GEMM1 -> SiLU -> feat tile (stored verbatim in swizzled layout)
//   B: feat tile -> GEMM2 -> IDWT -> out
// Each kernel: 256 thr, 64-pixel (one DWT row) tiles, grid 1024, 16x16x32 MFMA
// mt=4/nt=4 (R3's proven config), XOR-swizzled 32 KB LDS, no manual prefetch.
// Fused single-kernel fallback if ws_size is too small for feat (32 MB).

typedef __bf16 bf16x8 __attribute__((ext_vector_type(8)));
typedef float  f32x4  __attribute__((ext_vector_type(4)));

__device__ __forceinline__ unsigned short f2bf(float f) {
  __hip_bfloat16 h = __float2bfloat16(f);
  return __builtin_bit_cast(unsigned short, h);
}
__device__ __forceinline__ float bf2f(unsigned short s) {
  union { unsigned int i; float f; } v; v.i = ((unsigned int)s) << 16; return v.f;
}
__device__ __forceinline__ float silu(float f) {
  return f / (1.0f + __expf(-f));
}
// Swizzled flat index into a 64x256 bf16 tile: 16B unit XOR'd with pix&31.
__device__ __forceinline__ int sw(int pix, int k) {
  return pix * 256 + ((((k >> 3) ^ pix) & 31) << 3) + (k & 7);
}
__device__ __forceinline__ bf16x8 ldw8(const float* __restrict__ p) {  // f32 fallback
  const float4 a = *(const float4*)p;
  const float4 b = *(const float4*)(p + 4);
  bf16x8 r;
  r[0] = (__bf16)a.x; r[1] = (__bf16)a.y; r[2] = (__bf16)a.z; r[3] = (__bf16)a.w;
  r[4] = (__bf16)b.x; r[5] = (__bf16)b.y; r[6] = (__bf16)b.z; r[7] = (__bf16)b.w;
  return r;
}

// Prelude: f32 -> bf16 weight conversion into workspace.
__global__ __launch_bounds__(256) void cvt_w(const float* __restrict__ w1,
                                             const float* __restrict__ w2,
                                             unsigned short* __restrict__ o) {
  const int i = (blockIdx.x * 256 + threadIdx.x) * 4;  // grid 64 x 256 covers 65536
  const float4 a = *(const float4*)(w1 + i);
  const float4 b = *(const float4*)(w2 + i);
  *(ushort4*)(o + i)         = make_ushort4(f2bf(a.x), f2bf(a.y), f2bf(a.z), f2bf(a.w));
  *(ushort4*)(o + 65536 + i) = make_ushort4(f2bf(b.x), f2bf(b.y), f2bf(b.z), f2bf(b.w));
}

// ---------------------------------------------------------------------------
// Kernel A: DWT -> GEMM1 -> SiLU -> feat tile to workspace (swizzled layout).
// ---------------------------------------------------------------------------
__global__ __launch_bounds__(256, 4)
void dwt_gemm1(const float* __restrict__ x,
               const unsigned short* __restrict__ w1,
               const float* __restrict__ b1,
               unsigned short* __restrict__ featg)
{
  __shared__ unsigned short lds[64 * 256];  // 32 KiB

  const int t  = threadIdx.x;
  const int n  = blockIdx.x >> 6;
  const int hh = blockIdx.x & 63;
  const int ww = t & 63;
  const int cg = t >> 6;

  // Phase 1: Haar DWT -> lds[ww][q*64+c] (swizzled)
  {
    const float* xb = x + ((size_t)n * 64 * 128 + (size_t)(2 * hh)) * 128 + 2 * ww;
    float2 r0v[16], r1v[16];
    #pragma unroll
    for (int j = 0; j < 4; ++j)
      #pragma unroll
      for (int ci = 0; ci < 4; ++ci) {
        const float* p = xb + (size_t)((cg + 4 * j) * 4 + ci) * (128 * 128);
        r0v[j * 4 + ci] = *(const float2*)p;
        r1v[j * 4 + ci] = *(const float2*)(p + 128);
      }
    #pragma unroll
    for (int j = 0; j < 4; ++j) {
      const int c0 = (cg + 4 * j) * 4;
      float qv[4][4];
      #pragma unroll
      for (int ci = 0; ci < 4; ++ci) {
        const float x1 = r0v[j * 4 + ci].x, x3 = r0v[j * 4 + ci].y;
        const float x2 = r1v[j * 4 + ci].x, x4 = r1v[j * 4 + ci].y;
        qv[0][ci] = 0.5f * ((x1 + x2) + (x3 + x4));
        qv[1][ci] = 0.5f * ((x3 + x4) - (x1 + x2));
        qv[2][ci] = 0.5f * ((x2 + x4) - (x1 + x3));
        qv[3][ci] = 0.5f * ((x1 + x4) - (x2 + x3));
      }
      #pragma unroll
      for (int q = 0; q < 4; ++q) {
        ushort4 v = make_ushort4(f2bf(qv[q][0]), f2bf(qv[q][1]), f2bf(qv[q][2]), f2bf(qv[q][3]));
        *(ushort4*)(&lds[sw(ww, q * 64 + c0)]) = v;
      }
    }
  }
  __syncthreads();

  const int wv   = t >> 6;
  const int r    = t & 15;
  const int quad = (t & 63) >> 4;

  // Phase 2: GEMM1 + bias + SiLU -> lds[pix][o] (swizzled)
  {
    f32x4 acc[4][4];
    #pragma unroll
    for (int mt = 0; mt < 4; ++mt)
      #pragma unroll
      for (int nt = 0; nt < 4; ++nt)
        acc[mt][nt] = (f32x4){0.0f, 0.0f, 0.0f, 0.0f};

    const unsigned short* wA = w1 + (wv * 64 + r) * 256 + quad * 8;
    #pragma unroll
    for (int k0 = 0; k0 < 256; k0 += 32) {
      bf16x8 a[4], b[4];
      #pragma unroll
      for (int mt = 0; mt < 4; ++mt)
        a[mt] = *(const bf16x8*)(wA + mt * (16 * 256) + k0);
      #pragma unroll
      for (int nt = 0; nt < 4; ++nt)
        b[nt] = *(const bf16x8*)(&lds[sw(nt * 16 + r, quad * 8 + k0)]);
      #pragma unroll
      for (int mt = 0; mt < 4; ++mt)
        #pragma unroll
        for (int nt = 0; nt < 4; ++nt)
          acc[mt][nt] = __builtin_amdgcn_mfma_f32_16x16x32_bf16(a[mt], b[nt], acc[mt][nt], 0, 0, 0);
    }
    __syncthreads();  // K-loop LDS reads done

    #pragma unroll
    for (int mt = 0; mt < 4; ++mt) {
      const int ob = wv * 64 + mt * 16 + quad * 4;
      const float4 bb = *(const float4*)(b1 + ob);
      #pragma unroll
      for (int nt = 0; nt < 4; ++nt) {
        const int pix = nt * 16 + r;
        ushort4 v;
        v.x = f2bf(silu(acc[mt][nt][0] + bb.x));
        v.y = f2bf(silu(acc[mt][nt][1] + bb.y));
        v.z = f2bf(silu(acc[mt][nt][2] + bb.z));
        v.w = f2bf(silu(acc[mt][nt][3] + bb.w));
        *(ushort4*)(&lds[sw(pix, ob)]) = v;
      }
    }
  }
  __syncthreads();

  // Phase 3: copy the 32 KB tile verbatim to workspace (coalesced dwordx4).
  {
    unsigned short* dst = featg + (size_t)blockIdx.x * (64 * 256);
    #pragma unroll
    for (int it = 0; it < 8; ++it) {
      const int off = it * 2048 + t * 8;  // u16 units, 16B-aligned
      *(uint4*)(dst + off) = *(const uint4*)(&lds[off]);
    }
  }
}

// ---------------------------------------------------------------------------
// Kernel B: feat tile from workspace -> GEMM2 -> IDWT -> out.
// ---------------------------------------------------------------------------
__global__ __launch_bounds__(256, 4)
void gemm2_idwt(const unsigned short* __restrict__ featg,
                const unsigned short* __restrict__ w2,
                const float* __restrict__ b2,
                float* __restrict__ out)
{
  __shared__ unsigned short lds[64 * 256];  // 32 KiB

  const int t  = threadIdx.x;
  const int n  = blockIdx.x >> 6;
  const int hh = blockIdx.x & 63;
  const int ww = t & 63;
  const int cg = t >> 6;

  // Phase 0: stage the 32 KB feat tile (verbatim; already swizzled).
  {
    const unsigned short* src = featg + (size_t)blockIdx.x * (64 * 256);
    #pragma unroll
    for (int it = 0; it < 8; ++it) {
      const int off = it * 2048 + t * 8;
      *(uint4*)(&lds[off]) = *(const uint4*)(src + off);
    }
  }
  __syncthreads();

  const int wv   = t >> 6;
  const int r    = t & 15;
  const int quad = (t & 63) >> 4;

  // Phase 1: GEMM2 + bias -> lds[pix][c4] (swizzled)
  {
    f32x4 acc[4][4];
    #pragma unroll
    for (int mt = 0; mt < 4; ++mt)
      #pragma unroll
      for (int nt = 0; nt < 4; ++nt)
        acc[mt][nt] = (f32x4){0.0f, 0.0f, 0.0f, 0.0f};

    const unsigned short* wA = w2 + (wv * 64 + r) * 256 + quad * 8;
    #pragma unroll
    for (int k0 = 0; k0 < 256; k0 += 32) {
      bf16x8 a[4], b[4];
      #pragma unroll
      for (int mt = 0; mt < 4; ++mt)
        a[mt] = *(const bf16x8*)(wA + mt * (16 * 256) + k0);
      #pragma unroll
      for (int nt = 0; nt < 4; ++nt)
        b[nt] = *(const bf16x8*)(&lds[sw(nt * 16 + r, quad * 8 + k0)]);
      #pragma unroll
      for (int mt = 0; mt < 4; ++mt)
        #pragma unroll
        for (int nt = 0; nt < 4; ++nt)
          acc[mt][nt] = __builtin_amdgcn_mfma_f32_16x16x32_bf16(a[mt], b[nt], acc[mt][nt], 0, 0, 0);
    }
    __syncthreads();  // K-loop LDS reads done

    #pragma unroll
    for (int mt = 0; mt < 4; ++mt) {
      const int cb = wv * 64 + mt * 16 + quad * 4;
      const float4 bb = *(const float4*)(b2 + cb);
      #pragma unroll
      for (int nt = 0; nt < 4; ++nt) {
        const int pix = nt * 16 + r;
        ushort4 v;
        v.x = f2bf(acc[mt][nt][0] + bb.x);
        v.y = f2bf(acc[mt][nt][1] + bb.y);
        v.z = f2bf(acc[mt][nt][2] + bb.z);
        v.w = f2bf(acc[mt][nt][3] + bb.w);
        *(ushort4*)(&lds[sw(pix, cb)]) = v;
      }
    }
  }
  __syncthreads();

  // Phase 2: IDWT + coalesced float2 stores.
  {
    float* ob_ = out + ((size_t)n * 64 * 128 + (size_t)(2 * hh)) * 128 + 2 * ww;
    #pragma unroll
    for (int j = 0; j < 4; ++j) {
      const int c0 = (cg + 4 * j) * 4;
      unsigned short yb[4][4];
      #pragma unroll
      for (int q = 0; q < 4; ++q) {
        const ushort4 v = *(const ushort4*)(&lds[sw(ww, q * 64 + c0)]);
        yb[q][0] = v.x; yb[q][1] = v.y; yb[q][2] = v.z; yb[q][3] = v.w;
      }
      #pragma unroll
      for (int ci = 0; ci < 4; ++ci) {
        const float y1 = 0.5f * bf2f(yb[0][ci]);
        const float y2 = 0.5f * bf2f(yb[1][ci]);
        const float y3 = 0.5f * bf2f(yb[2][ci]);
        const float y4 = 0.5f * bf2f(yb[3][ci]);
        const float s14 = y1 + y4, s23 = y2 + y3;
        const float d14 = y1 - y4, d23 = y2 - y3;
        const float oa  = s14 - s23;  // (2hh,   2ww)
        const float oc  = d14 + d23;  // (2hh,   2ww+1)
        const float obv = d14 - d23;  // (2hh+1, 2ww)
        const float od  = s14 + s23;  // (2hh+1, 2ww+1)
        float* prow = ob_ + (size_t)(c0 + ci) * (128 * 128);
        *(float2*)prow         = make_float2(oa, oc);
        *(float2*)(prow + 128) = make_float2(obv, od);
      }
    }
  }
}

// ---------------------------------------------------------------------------
// Fused fallback (R3-style with swizzle) — used only if ws can't hold feat.
// ---------------------------------------------------------------------------
__global__ __launch_bounds__(256, 4)
void wavelet_fused_f32(const float* __restrict__ x,
                       const float* __restrict__ w1,
                       const float* __restrict__ b1,
                       const float* __restrict__ w2,
                       const float* __restrict__ b2,
                       float* __restrict__ out)
{
  __shared__ unsigned short lds[64 * 256];
  const int t  = threadIdx.x;
  const int n  = blockIdx.x >> 6;
  const int hh = blockIdx.x & 63;
  const int ww = t & 63;
  const int cg = t >> 6;
  {
    const float* xb = x + ((size_t)n * 64 * 128 + (size_t)(2 * hh)) * 128 + 2 * ww;
    #pragma unroll
    for (int j = 0; j < 4; ++j) {
      const int c0 = (cg + 4 * j) * 4;
      float qv[4][4];
      #pragma unroll
      for (int ci = 0; ci < 4; ++ci) {
        const float* p = xb + (size_t)(c0 + ci) * (128 * 128);
        const float2 r0 = *(const float2*)p;
        const float2 r1 = *(const float2*)(p + 128);
        const float x1 = r0.x, x3 = r0.y, x2 = r1.x, x4 = r1.y;
        qv[0][ci] = 0.5f * ((x1 + x2) + (x3 + x4));
        qv[1][ci] = 0.5f * ((x3 + x4) - (x1 + x2));
        qv[2][ci] = 0.5f * ((x2 + x4) - (x1 + x3));
        qv[3][ci] = 0.5f * ((x1 + x4) - (x2 + x3));
      }
      #pragma unroll
      for (int q = 0; q < 4; ++q)
        *(ushort4*)(&lds[sw(ww, q * 64 + c0)]) =
            make_ushort4(f2bf(qv[q][0]), f2bf(qv[q][1]), f2bf(qv[q][2]), f2bf(qv[q][3]));
    }
  }
  __syncthreads();
  const int wv = t >> 6, r = t & 15, quad = (t & 63) >> 4;
  {
    f32x4 acc[4][4];
    #pragma unroll
    for (int mt = 0; mt < 4; ++mt)
      #pragma unroll
      for (int nt = 0; nt < 4; ++nt) acc[mt][nt] = (f32x4){0,0,0,0};
    const float* wA = w1 + (wv * 64 + r) * 256 + quad * 8;
    #pragma unroll
    for (int k0 = 0; k0 < 256; k0 += 32) {
      bf16x8 a[4], b[4];
      #pragma unroll
      for (int mt = 0; mt < 4; ++mt) a[mt] = ldw8(wA + mt * (16 * 256) + k0);
      #pragma unroll
      for (int nt = 0; nt < 4; ++nt) b[nt] = *(const bf16x8*)(&lds[sw(nt * 16 + r, quad * 8 + k0)]);
      #pragma unroll
      for (int mt = 0; mt < 4; ++mt)
        #pragma unroll
        for (int nt = 0; nt < 4; ++nt)
          acc[mt][nt] = __builtin_amdgcn_mfma_f32_16x16x32_bf16(a[mt], b[nt], acc[mt][nt], 0, 0, 0);
    }
    __syncthreads();
    #pragma unroll
    for (int mt = 0; mt < 4; ++mt) {
      const int ob = wv * 64 + mt * 16 + quad * 4;
      const float4 bb = *(const float4*)(b1 + ob);
      #pragma unroll
      for (int nt = 0; nt < 4; ++nt) {
        const int pix = nt * 16 + r;
        ushort4 v;
        v.x = f2bf(silu(acc[mt][nt][0] + bb.x));
        v.y = f2bf(silu(acc[mt][nt][1] + bb.y));
        v.z = f2bf(silu(acc[mt][nt][2] + bb.z));
        v.w = f2bf(silu(acc[mt][nt][3] + bb.w));
        *(ushort4*)(&lds[sw(pix, ob)]) = v;
      }
    }
  }
  __syncthreads();
  {
    f32x4 acc[4][4];
    #pragma unroll
    for (int mt = 0; mt < 4; ++mt)
      #pragma unroll
      for (int nt = 0; nt < 4; ++nt) acc[mt][nt] = (f32x4){0,0,0,0};
    const float* wA = w2 + (wv * 64 + r) * 256 + quad * 8;
    #pragma unroll
    for (int k0 = 0; k0 < 256; k0 += 32) {
      bf16x8 a[4], b[4];
      #pragma unroll
      for (int mt = 0; mt < 4; ++mt) a[mt] = ldw8(wA + mt * (16 * 256) + k0);
      #pragma unroll
      for (int nt = 0; nt < 4; ++nt) b[nt] = *(const bf16x8*)(&lds[sw(nt * 16 + r, quad * 8 + k0)]);
      #pragma unroll
      for (int mt = 0; mt < 4; ++mt)
        #pragma unroll
        for (int nt = 0; nt < 4; ++nt)
          acc[mt][nt] = __builtin_amdgcn_mfma_f32_16x16x32_bf16(a[mt], b[nt], acc[mt][nt], 0, 0, 0);
    }
    __syncthreads();
    #pragma unroll
    for (int mt = 0; mt < 4; ++mt) {
      const int cb = wv * 64 + mt * 16 + quad * 4;
      const float4 bb = *(const float4*)(b2 + cb);
      #pragma unroll
      for (int nt = 0; nt < 4; ++nt) {
        const int pix = nt * 16 + r;
        ushort4 v;
        v.x = f2bf(acc[mt][nt][0] + bb.x);
        v.y = f2bf(acc[mt][nt][1] + bb.y);
        v.z = f2bf(acc[mt][nt][2] + bb.z);
        v.w = f2bf(acc[mt][nt][3] + bb.w);
        *(ushort4*)(&lds[sw(pix, cb)]) = v;
      }
    }
  }
  __syncthreads();
  {
    float* ob_ = out + ((size_t)n * 64 * 128 + (size_t)(2 * hh)) * 128 + 2 * ww;
    #pragma unroll
    for (int j = 0; j < 4; ++j) {
      const int c0 = (cg + 4 * j) * 4;
      unsigned short yb[4][4];
      #pragma unroll
      for (int q = 0; q < 4; ++q) {
        const ushort4 v = *(const ushort4*)(&lds[sw(ww, q * 64 + c0)]);
        yb[q][0] = v.x; yb[q][1] = v.y; yb[q][2] = v.z; yb[q][3] = v.w;
      }
      #pragma unroll
      for (int ci = 0; ci < 4; ++ci) {
        const float y1 = 0.5f * bf2f(yb[0][ci]);
        const float y2 = 0.5f * bf2f(yb[1][ci]);
        const float y3 = 0.5f * bf2f(yb[2][ci]);
        const float y4 = 0.5f * bf2f(yb[3][ci]);
        const float s14 = y1 + y4, s23 = y2 + y3;
        const float d14 = y1 - y4, d23 = y2 - y3;
        float* prow = ob_ + (size_t)(c0 + ci) * (128 * 128);
        *(float2*)prow         = make_float2(s14 - s23, d14 + d23);
        *(float2*)(prow + 128) = make_float2(d14 - d23, s14 + s23);
      }
    }
  }
}

extern "C" void kernel_launch(void* const* d_in, const int* in_sizes, int n_in,
                              void* d_out, int out_size, void* d_ws, size_t ws_size,
                              hipStream_t stream) {
  (void)in_sizes; (void)n_in; (void)out_size;
  const float* x  = (const float*)d_in[0];
  const float* w1 = (const float*)d_in[1];
  const float* b1 = (const float*)d_in[2];
  const float* w2 = (const float*)d_in[3];
  const float* b2 = (const float*)d_in[4];
  float* o = (float*)d_out;

  const size_t wbytes    = 2u * 65536u * sizeof(unsigned short);      // 256 KB bf16 weights
  const size_t featbytes = (size_t)1024 * 64 * 256 * sizeof(unsigned short);  // 32 MB

  if (ws_size >= wbytes + featbytes) {
    unsigned short* wb    = (unsigned short*)d_ws;
    unsigned short* featg = wb + 2u * 65536u;
    cvt_w<<<dim3(64), dim3(256), 0, stream>>>(w1, w2, wb);
    dwt_gemm1<<<dim3(1024), dim3(256), 0, stream>>>(x, wb, b1, featg);
    gemm2_idwt<<<dim3(1024), dim3(256), 0, stream>>>(featg, wb + 65536, b2, o);
  } else {
    wavelet_fused_f32<<<dim3(1024), dim3(256), 0, stream>>>(x, w1, b1, w2, b2, o);
  }
}